// Round 1
// baseline (370.811 us; speedup 1.0000x reference)
//
#include <hip/hip_runtime.h>
#include <math.h>

#define NEGV 1000000000000.0f

// ---------------- Kernel 1: h = x@W1+b1 (2-way split-k); RoPE -> qw, kwt; bias ----------------
// grid 256 x 256 thr; block = 16 rows. Thread = (kh 0/1) x (rg 0..3 -> 4 rows) x (jc 0..31 -> 4 cols),
// each computes a 4x4 partial over 384 k; halves per-wave W1 VMEM traffic vs 2x4 full-k tiling.
// kw is now written K-MAJOR (kwt[64][4096]) so k2 can stage it densely.
__global__ __launch_bounds__(256) void k1_fused(
    const float* __restrict__ x,    // (4096, 768)
    const float* __restrict__ W1,   // (768, 128)
    const float* __restrict__ b1,   // (128)
    const float* __restrict__ W2,   // (128, 32)
    const float* __restrict__ b2,   // (32)
    float* __restrict__ qw,         // (4096, 64) row-major
    float* __restrict__ kwt,        // (64, 4096) k-major
    float* __restrict__ bias)       // (4, 32, 1024)
{
    __shared__ float xs[16][772];       // 16 x 768, +4 pad
    __shared__ float hs[2][16][132];    // two k-half partials of h
    const int t    = threadIdx.x;
    const int row0 = blockIdx.x * 16;

    // ---- stage x tile (16 x 768) via coalesced float4 ----
    {
        const float4* xg = (const float4*)(x + (size_t)row0 * 768);
        #pragma unroll
        for (int it = 0; it < 12; ++it) {
            const int idx = t + it * 256;            // 0..3071
            const int r = idx / 192, c4 = idx - r * 192;
            const float4 v = xg[idx];
            *(float4*)&xs[r][c4 * 4] = v;
        }
    }
    __syncthreads();

    // ---- split-k GEMM ----
    {
        const int jc = (t & 31) * 4;        // 4 cols
        const int rg = ((t >> 5) & 3) * 4;  // 4 rows
        const int kh = t >> 7;              // k half (wave-uniform)
        const int k0 = kh * 384;

        float acc[4][4] = {{0.f, 0.f, 0.f, 0.f}};
        #pragma unroll 2
        for (int k = 0; k < 384; k += 4) {
            const float4 xv0 = *(const float4*)&xs[rg + 0][k0 + k];
            const float4 xv1 = *(const float4*)&xs[rg + 1][k0 + k];
            const float4 xv2 = *(const float4*)&xs[rg + 2][k0 + k];
            const float4 xv3 = *(const float4*)&xs[rg + 3][k0 + k];
            const float xa[4][4] = {
                {xv0.x, xv0.y, xv0.z, xv0.w},
                {xv1.x, xv1.y, xv1.z, xv1.w},
                {xv2.x, xv2.y, xv2.z, xv2.w},
                {xv3.x, xv3.y, xv3.z, xv3.w}};
            #pragma unroll
            for (int kk = 0; kk < 4; ++kk) {
                const float4 w = *(const float4*)&W1[(size_t)(k0 + k + kk) * 128 + jc];
                const float wv[4] = {w.x, w.y, w.z, w.w};
                #pragma unroll
                for (int i = 0; i < 4; ++i) {
                    #pragma unroll
                    for (int c = 0; c < 4; ++c)
                        acc[i][c] = fmaf(xa[i][kk], wv[c], acc[i][c]);
                }
            }
        }
        const float4 bv = *(const float4*)&b1[jc];
        const float bvv[4] = {bv.x, bv.y, bv.z, bv.w};
        #pragma unroll
        for (int i = 0; i < 4; ++i) {
            float4 hv;
            hv.x = acc[i][0] + (kh == 0 ? bvv[0] : 0.f);
            hv.y = acc[i][1] + (kh == 0 ? bvv[1] : 0.f);
            hv.z = acc[i][2] + (kh == 0 ? bvv[2] : 0.f);
            hv.w = acc[i][3] + (kh == 0 ? bvv[3] : 0.f);
            *(float4*)&hs[kh][rg + i][jc] = hv;
        }
    }
    __syncthreads();

    // ---- reduce the two k-half partials into hs[0] ----
    #pragma unroll
    for (int it = 0; it < 8; ++it) {
        const int idx = t + it * 256;        // 0..2047
        const int r = idx >> 7, c = idx & 127;
        hs[0][r][c] += hs[1][r][c];
    }
    __syncthreads();

    // ---- RoPE, loop A: qw (row-major, c fast across lanes -> coalesced) ----
    #pragma unroll
    for (int it = 0; it < 4; ++it) {
        const int idx = t + it * 256;        // 0..1023 = r*64 + c
        const int c = idx & 63, r = idx >> 6;
        const int s = (row0 + r) & 1023;
        const int f = c & 31;
        const float invf = exp2f(-0.4152410118609203f * (float)f); // 10000^(-f/32)
        const float ang = (float)s * invf;
        float sn, cs;
        sincosf(ang, &sn, &cs);
        const int   pc  = (c & 1) ? (c - 1) : (c + 1);
        const float sgn = (c & 1) ? sn : -sn;
        const float qv = fmaf(hs[0][r][2 * c], cs, hs[0][r][2 * pc] * sgn);
        qw[(size_t)(row0 + r) * 64 + c] = qv;
    }

    // ---- RoPE, loop B: kwt (k-major, row fast across lanes -> 64B chunks) ----
    #pragma unroll
    for (int it = 0; it < 4; ++it) {
        const int idx = t + it * 256;        // 0..1023 = c*16 + mi
        const int mi = idx & 15, c = idx >> 4;   // c 0..63
        const int s = (row0 + mi) & 1023;
        const int f = c & 31;
        const float invf = exp2f(-0.4152410118609203f * (float)f);
        const float ang = (float)s * invf;
        float sn, cs;
        sincosf(ang, &sn, &cs);
        const int   pc  = (c & 1) ? (c - 1) : (c + 1);
        const float sgn = (c & 1) ? sn : -sn;
        const float kv = fmaf(hs[0][mi][2 * c + 1], cs, hs[0][mi][2 * pc + 1] * sgn);
        kwt[(size_t)c * 4096 + row0 + mi] = kv;
    }

    // ---- bias[b][ch][s] = (h . W2[:,ch] + b2)/2 ; mi fast across lanes -> 64B chunks ----
    {
        const int s0 = row0 & 1023, bb = row0 >> 10;
        #pragma unroll
        for (int it = 0; it < 2; ++it) {
            const int idx = t + it * 256;    // 0..511 = c*16 + mi
            const int mi = idx & 15, c = idx >> 4;   // c 0..31
            float a = 0.f;
            #pragma unroll 4
            for (int k = 0; k < 128; ++k)
                a = fmaf(hs[0][mi][k], W2[k * 32 + c], a);
            bias[(size_t)(bb * 32 + c) * 1024 + s0 + mi] = (a + b2[c]) * 0.5f;
        }
    }
}

// ---------------- Kernel 2: out = qk/8 + bA[n] + bB[m], mask + causal ----------------
// grid (4, 64, 4) = (n-tile 256, m-tile 16, b); 256 thr. Thread = wave w (4 rows) x lane L
// (4 consecutive cols, n = n0 + 4L). Store inst = 64 lanes x 16B = 1KB CONTIGUOUS (was 256B
// chunks @4KB stride -> store-backpressure-bound at ~1.8 TB/s). K staged from kwt in two
// 32-k chunks, LDS [k][n] stride 260: read banks (4L+j)%32 optimal, writes dense b128.
__global__ __launch_bounds__(256, 4) void k2_outer(
    const float* __restrict__ qw,   // (4096, 64)
    const float* __restrict__ kwt,  // (64, 4096)
    const float* __restrict__ bias, // (4, 32, 1024)
    const float* __restrict__ mask, // (4, 1024)
    float* __restrict__ out)        // (4, 16, 1024, 1024)
{
    __shared__ float ks[32][260];   // k-chunk x n-tile, +4 pad (16B-aligned rows)
    __shared__ float qs[16][68];    // m x k(64)
    __shared__ float bBs[16][16];   // bias[b][2o+1][m-tile]

    const int t  = threadIdx.x;
    const int n0 = blockIdx.x * 256;
    const int m0 = blockIdx.y * 16;
    const int b  = blockIdx.z;
    const int L  = t & 63;          // lane: cols n0+4L..n0+4L+3
    const int w  = t >> 6;          // wave: rows m0+4w..m0+4w+3

    // ---- one-time stages: qs (16x64) and bBs (16x16) ----
    {
        const int r = t >> 4, kq = t & 15;
        *(float4*)&qs[r][kq * 4] =
            *(const float4*)&qw[(size_t)(b * 1024 + m0 + r) * 64 + kq * 4];
        bBs[r][kq] = bias[(size_t)(b * 32 + 2 * r + 1) * 1024 + m0 + kq];
    }

    float acc[4][4] = {{0.f, 0.f, 0.f, 0.f}};
    for (int kc = 0; kc < 2; ++kc) {
        if (kc) __syncthreads();             // previous chunk's readers done
        {   // stage ks chunk: k rows kc*32..+31, cols n0..n0+255 (dense, coalesced)
            const float4* kg4 = (const float4*)kwt;   // row stride 1024 float4
            const int col4 = (b * 1024 + n0) >> 2;
            #pragma unroll
            for (int it = 0; it < 8; ++it) {
                const int idx = t + it * 256;         // 0..2047 = kk*64 + nq
                const int kk = idx >> 6, nq = idx & 63;
                const float4 v = kg4[(size_t)(kc * 32 + kk) * 1024 + col4 + nq];
                *(float4*)&ks[kk][nq * 4] = v;
            }
        }
        __syncthreads();

        #pragma unroll
        for (int kg = 0; kg < 8; ++kg) {
            float4 kv[4];
            #pragma unroll
            for (int kk = 0; kk < 4; ++kk)
                kv[kk] = *(const float4*)&ks[kg * 4 + kk][4 * L];
            const float4 q0 = *(const float4*)&qs[4 * w + 0][kc * 32 + kg * 4];
            const float4 q1 = *(const float4*)&qs[4 * w + 1][kc * 32 + kg * 4];
            const float4 q2 = *(const float4*)&qs[4 * w + 2][kc * 32 + kg * 4];
            const float4 q3 = *(const float4*)&qs[4 * w + 3][kc * 32 + kg * 4];
            const float qa[4][4] = {
                {q0.x, q0.y, q0.z, q0.w},
                {q1.x, q1.y, q1.z, q1.w},
                {q2.x, q2.y, q2.z, q2.w},
                {q3.x, q3.y, q3.z, q3.w}};
            #pragma unroll
            for (int kk = 0; kk < 4; ++kk) {
                const float kvv[4] = {kv[kk].x, kv[kk].y, kv[kk].z, kv[kk].w};
                #pragma unroll
                for (int i = 0; i < 4; ++i) {
                    #pragma unroll
                    for (int c = 0; c < 4; ++c)
                        acc[i][c] = fmaf(qa[i][kk], kvv[c], acc[i][c]);
                }
            }
        }
    }

    // ---- epilogue: precompute mask+causal terms, then 16 planes x 4 rows of 1KB stores ----
    const float4 pv = *(const float4*)&mask[b * 1024 + n0 + 4 * L];
    const float p[4] = {pv.x, pv.y, pv.z, pv.w};
    float mneg[4][4];
    #pragma unroll
    for (int i = 0; i < 4; ++i) {
        const int mg = m0 + 4 * w + i;
        #pragma unroll
        for (int c = 0; c < 4; ++c) {
            float wsub = (1.f - p[c]) * NEGV;
            if (n0 + 4 * L + c < mg) wsub += NEGV;   // tril(-1) causal
            mneg[i][c] = -wsub;
        }
    }
    float* outb = out + (size_t)b * 16 * 1024 * 1024 + n0 + 4 * L;
    #pragma unroll 2
    for (int o = 0; o < 16; ++o) {
        const float4 av = *(const float4*)&bias[(size_t)(b * 32 + 2 * o) * 1024 + n0 + 4 * L];
        const float a[4] = {av.x, av.y, av.z, av.w};
        #pragma unroll
        for (int i = 0; i < 4; ++i) {
            const int mg = m0 + 4 * w + i;
            const float vb = bBs[o][4 * w + i];
            float4 r4;
            r4.x = fmaf(fmaf(acc[i][0], 0.125f, a[0] + vb), p[0], mneg[i][0]);
            r4.y = fmaf(fmaf(acc[i][1], 0.125f, a[1] + vb), p[1], mneg[i][1]);
            r4.z = fmaf(fmaf(acc[i][2], 0.125f, a[2] + vb), p[2], mneg[i][2]);
            r4.w = fmaf(fmaf(acc[i][3], 0.125f, a[3] + vb), p[3], mneg[i][3]);
            *(float4*)&outb[(size_t)(o * 1024 + mg) * 1024] = r4;
        }
    }
}

extern "C" void kernel_launch(void* const* d_in, const int* in_sizes, int n_in,
                              void* d_out, int out_size, void* d_ws, size_t ws_size,
                              hipStream_t stream) {
    const float* x    = (const float*)d_in[0];
    const float* mask = (const float*)d_in[1];
    const float* W1   = (const float*)d_in[2];
    const float* b1   = (const float*)d_in[3];
    const float* W2   = (const float*)d_in[4];
    const float* b2   = (const float*)d_in[5];
    float* out = (float*)d_out;

    float* ws   = (float*)d_ws;
    float* qw   = ws;                       // 4096*64 floats, row-major
    float* kwt  = ws + 4096 * 64;           // 64*4096 floats, k-major
    float* bias = ws + 2 * 4096 * 64;       // 4*32*1024 floats

    hipLaunchKernelGGL(k1_fused, dim3(256), dim3(256), 0, stream,
                       x, W1, b1, W2, b2, qw, kwt, bias);
    hipLaunchKernelGGL(k2_outer, dim3(4, 64, 4), dim3(256), 0, stream,
                       qw, kwt, bias, mask, out);
}